// Round 5
// baseline (500.236 us; speedup 1.0000x reference)
//
#include <hip/hip_runtime.h>
#include <math.h>

#define H 128

typedef _Float16 half8 __attribute__((ext_vector_type(8)));
typedef float f32x16 __attribute__((ext_vector_type(16)));

// ---------------- CSR build ----------------

__global__ __launch_bounds__(256) void zero_ints(int* __restrict__ p, int n) {
    int i = blockIdx.x * 256 + threadIdx.x;
    if (i < n) p[i] = 0;
}

__global__ __launch_bounds__(256) void hist_deg(const int* __restrict__ ei, int E,
                                                int* __restrict__ deg) {
    int e = blockIdx.x * 256 + threadIdx.x;
    if (e < E) atomicAdd(&deg[ei[E + e]], 1);  // dst row of edge_index
}

__global__ __launch_bounds__(256) void block_sums(const int* __restrict__ deg,
                                                  int* __restrict__ bsum, int N) {
    __shared__ int part[4];
    int tid = threadIdx.x;
    int i = blockIdx.x * 256 + tid;
    int v = (i < N) ? deg[i] : 0;
#pragma unroll
    for (int off = 32; off > 0; off >>= 1) v += __shfl_down(v, off, 64);
    if ((tid & 63) == 0) part[tid >> 6] = v;
    __syncthreads();
    if (tid == 0) bsum[blockIdx.x] = part[0] + part[1] + part[2] + part[3];
}

__global__ __launch_bounds__(64) void scan_bsum(const int* __restrict__ bsum,
                                                int* __restrict__ bbase, int NB,
                                                int* __restrict__ totalOut) {
    int lane = threadIdx.x;
    int base = 0;
    for (int s0 = 0; s0 < NB; s0 += 64) {
        int i = s0 + lane;
        int v = (i < NB) ? bsum[i] : 0;
        int incl = v;
#pragma unroll
        for (int off = 1; off < 64; off <<= 1) {
            int t = __shfl_up(incl, off, 64);
            if (lane >= off) incl += t;
        }
        if (i < NB) bbase[i] = base + incl - v;
        base += __shfl(incl, 63, 64);
    }
    if (lane == 0) *totalOut = base;  // offsets[N] = E
}

__global__ __launch_bounds__(256) void scan_within(const int* __restrict__ deg,
                                                   const int* __restrict__ bbase,
                                                   int* __restrict__ offsets, int N) {
    __shared__ int buf[256];
    int tid = threadIdx.x;
    int i = blockIdx.x * 256 + tid;
    int v = (i < N) ? deg[i] : 0;
    int incl = v;
    buf[tid] = v;
    __syncthreads();
#pragma unroll
    for (int off = 1; off < 256; off <<= 1) {
        int t = (tid >= off) ? buf[tid - off] : 0;
        __syncthreads();
        incl += t;
        buf[tid] = incl;
        __syncthreads();
    }
    if (i < N) offsets[i] = bbase[blockIdx.x] + incl - v;  // exclusive scan
}

__global__ __launch_bounds__(256) void fill_adj(const int* __restrict__ ei, int E,
                                                const int* __restrict__ offsets,
                                                int* __restrict__ cursor,
                                                int* __restrict__ adj) {
    int e = blockIdx.x * 256 + threadIdx.x;
    if (e < E) {
        int s = ei[e];
        int d = ei[E + e];
        int pos = atomicAdd(&cursor[d], 1);
        adj[offsets[d] + pos] = s;
    }
}

// ---------------- query normalization ----------------

__global__ __launch_bounds__(128) void prep_query(const float* __restrict__ query,
                                                  float* __restrict__ qn) {
    int g = blockIdx.x;
    int f = threadIdx.x;
    float v = query[g * H + f];
    float ss = v * v;
#pragma unroll
    for (int off = 32; off > 0; off >>= 1) ss += __shfl_xor(ss, off, 64);
    __shared__ float part[2];
    if ((f & 63) == 0) part[f >> 6] = ss;
    __syncthreads();
    float tot = part[0] + part[1];
    qn[g * H + f] = v / fmaxf(sqrtf(tot), 1e-12f);
}

// ---------------- weight split (plain [mat][hl][n][k] layout) ----------------
// mat order: Wl0,Wr0,Wl1,Wr1,Wl2,Wr2,Wlin. Per mat: hi image 16 KB + lo 16 KB.

__global__ __launch_bounds__(256) void prep_wsplit(const float* __restrict__ Wl,
                                                   const float* __restrict__ Wr,
                                                   const float* __restrict__ Wlin,
                                                   _Float16* __restrict__ img) {
    int gidx = blockIdx.x * 256 + threadIdx.x;
    if (gidx >= 7 * 128 * 16) return;
    int mat = gidx / 2048;
    int rem = gidx - mat * 2048;
    int n = rem >> 4;
    int g16 = rem & 15;
    const float* src = (mat == 6) ? Wlin
                     : ((mat & 1) ? Wr + (mat >> 1) * H * H : Wl + (mat >> 1) * H * H);
    const float* p = src + n * H + g16 * 8;
    half8 h, l;
#pragma unroll
    for (int j = 0; j < 8; ++j) {
        float v = p[j];
        _Float16 hh = (_Float16)v;
        h[j] = hh;
        l[j] = (_Float16)(v - (float)hh);
    }
    size_t base = (size_t)mat * 32768 + (size_t)n * 128 + g16 * 8;
    *(half8*)(img + base) = h;
    *(half8*)(img + base + 16384) = l;
}

// ---------------- initial activation split ----------------

__global__ __launch_bounds__(256) void split_x(const float4* __restrict__ x4,
                                               half8* __restrict__ xh,
                                               half8* __restrict__ xl, int n8) {
    int i = blockIdx.x * 256 + threadIdx.x;
    if (i >= n8) return;
    float4 u = x4[(size_t)i * 2], v = x4[(size_t)i * 2 + 1];
    float f[8] = {u.x, u.y, u.z, u.w, v.x, v.y, v.z, v.w};
    half8 h, l;
#pragma unroll
    for (int j = 0; j < 8; ++j) {
        _Float16 hh = (_Float16)f[j];
        h[j] = hh;
        l[j] = (_Float16)(f[j] - (float)hh);
    }
    xh[i] = h;
    xl[i] = l;
}

// ---------------- gather-max over CSR, split-fp16 in/out ----------------
// 16 lanes per node (half8 hi + half8 lo each = the node row), 16 nodes/block.
// Reconstruct v = hi + lo (exact fp32 sum of two fp16), max in fp32, re-split
// on write (RN16(max) reproduces the winning pair). deg==0 -> 0.

__global__ __launch_bounds__(256, 4) void gather_max_h(
    const half8* __restrict__ xh, const half8* __restrict__ xl,
    const int* __restrict__ offsets, const int* __restrict__ adj,
    half8* __restrict__ mh, half8* __restrict__ ml, int N) {
    int tid = threadIdx.x;
    int lf = tid & 15;
    int node = blockIdx.x * 16 + (tid >> 4);
    if (node >= N) return;
    int e0 = offsets[node], e1 = offsets[node + 1];
    float best[8];
#pragma unroll
    for (int j = 0; j < 8; ++j) best[j] = 0.f;
    if (e1 > e0) {
        float acc[4][8];
#pragma unroll
        for (int u = 0; u < 4; ++u)
#pragma unroll
            for (int j = 0; j < 8; ++j) acc[u][j] = -INFINITY;
        for (int base = e0; base < e1; base += 4) {
            int a[4];
#pragma unroll
            for (int u = 0; u < 4; ++u) {
                int ee = base + u;
                a[u] = adj[ee < e1 ? ee : e1 - 1];  // dupes are max-neutral
            }
            half8 hh[4], ll[4];
#pragma unroll
            for (int u = 0; u < 4; ++u) {
                hh[u] = xh[(size_t)a[u] * 16 + lf];
                ll[u] = xl[(size_t)a[u] * 16 + lf];
            }
#pragma unroll
            for (int u = 0; u < 4; ++u)
#pragma unroll
                for (int j = 0; j < 8; ++j) {
                    float r = (float)hh[u][j] + (float)ll[u][j];
                    acc[u][j] = fmaxf(acc[u][j], r);
                }
        }
#pragma unroll
        for (int j = 0; j < 8; ++j)
            best[j] = fmaxf(fmaxf(acc[0][j], acc[1][j]),
                            fmaxf(acc[2][j], acc[3][j]));
    }
    half8 h, l;
#pragma unroll
    for (int j = 0; j < 8; ++j) {
        _Float16 hh2 = (_Float16)best[j];
        h[j] = hh2;
        l[j] = (_Float16)(best[j] - (float)hh2);
    }
    mh[(size_t)node * 16 + lf] = h;
    ml[(size_t)node * 16 + lf] = l;
}

// ---------------- MFMA dual GEMM + bias + relu, pre-split operands ----------------
// relu(A0 @ W0^T + bias + A1 @ W1^T) via fp16 hi/lo x3 MFMA per pass.
// Block 256 = 4 waves = 4 col-quads of one 32-row stripe (A refetch L1-served).
// Wave tile 32x32, acc = 16 f32. No LDS, no barriers. 6252 waves total.

__global__ __launch_bounds__(256, 4) void gemm_mfma2(
    const half8* __restrict__ A0h, const half8* __restrict__ A0l,
    const half8* __restrict__ A1h, const half8* __restrict__ A1l,
    const half8* __restrict__ B0h, const half8* __restrict__ B0l,
    const half8* __restrict__ B1h, const half8* __restrict__ B1l,
    const float* __restrict__ bias, _Float16* __restrict__ Oh,
    _Float16* __restrict__ Ol, int N) {
    int tid = threadIdx.x;
    int w = tid >> 6;
    int lane = tid & 63;
    int l31 = lane & 31;
    int lhi = lane >> 5;
    int n0 = blockIdx.x * 32;
    int c0 = w * 32;

    int arow = n0 + l31;
    arow = arow < N ? arow : N - 1;
    int brow = c0 + l31;

    f32x16 acc;
    float bv = bias[c0 + l31];
#pragma unroll
    for (int r = 0; r < 16; ++r) acc[r] = bv;

#pragma unroll
    for (int kstep = 0; kstep < 8; ++kstep) {
        int g = kstep * 2 + lhi;
        size_t ai = (size_t)arow * 16 + g;
        size_t bi = (size_t)brow * 16 + g;
        half8 a0h = A0h[ai], a0l = A0l[ai];
        half8 a1h = A1h[ai], a1l = A1l[ai];
        half8 b0h = B0h[bi], b0l = B0l[bi];
        half8 b1h = B1h[bi], b1l = B1l[bi];
        acc = __builtin_amdgcn_mfma_f32_32x32x16_f16(a0h, b0h, acc, 0, 0, 0);
        acc = __builtin_amdgcn_mfma_f32_32x32x16_f16(a0l, b0h, acc, 0, 0, 0);
        acc = __builtin_amdgcn_mfma_f32_32x32x16_f16(a0h, b0l, acc, 0, 0, 0);
        acc = __builtin_amdgcn_mfma_f32_32x32x16_f16(a1h, b1h, acc, 0, 0, 0);
        acc = __builtin_amdgcn_mfma_f32_32x32x16_f16(a1l, b1h, acc, 0, 0, 0);
        acc = __builtin_amdgcn_mfma_f32_32x32x16_f16(a1h, b1l, acc, 0, 0, 0);
    }

    // C/D: col = l31 (+c0), row = (r&3) + 8*(r>>2) + 4*lhi (+n0)
#pragma unroll
    for (int r = 0; r < 16; ++r) {
        int row = n0 + (r & 3) + 8 * (r >> 2) + 4 * lhi;
        if (row < N) {
            float y = fmaxf(acc[r], 0.f);
            _Float16 h = (_Float16)y;
            Oh[(size_t)row * H + c0 + l31] = h;
            Ol[(size_t)row * H + c0 + l31] = (_Float16)(y - (float)h);
        }
    }
}

// ---------------- MFMA final linear + cosine, pre-split A ----------------
// Block 256 = 4 waves, each wave an independent 32-row stripe, full 128 cols
// (nt=4) so the cosine reduction stays within 32 lanes. qn staged in LDS.

__global__ __launch_bounds__(256, 2) void final_mfma2(
    const half8* __restrict__ Ah, const half8* __restrict__ Al,
    const half8* __restrict__ Bh, const half8* __restrict__ Bl,
    const float* __restrict__ blin, const float* __restrict__ qn,
    const int* __restrict__ bv, float* __restrict__ out, int N, int G) {
    __shared__ float qs[8 * H];
    int tid = threadIdx.x;
    int ng = G * H;
    if (ng > 8 * H) ng = 8 * H;
    for (int i = tid; i < ng; i += 256) qs[i] = qn[i];
    __syncthreads();

    int w = tid >> 6;
    int lane = tid & 63;
    int l31 = lane & 31;
    int lhi = lane >> 5;
    int n0 = blockIdx.x * 128 + w * 32;

    int arow = n0 + l31;
    arow = arow < N ? arow : N - 1;
    int gl = bv[arow];  // per-lane cache of this stripe's graph ids

    f32x16 acc[4];
#pragma unroll
    for (int nt = 0; nt < 4; ++nt) {
        float b = blin[nt * 32 + l31];
#pragma unroll
        for (int r = 0; r < 16; ++r) acc[nt][r] = b;
    }

#pragma unroll
    for (int kstep = 0; kstep < 8; ++kstep) {
        int g = kstep * 2 + lhi;
        size_t ai = (size_t)arow * 16 + g;
        half8 ah = Ah[ai], al = Al[ai];
#pragma unroll
        for (int nt = 0; nt < 4; ++nt) {
            size_t bi = (size_t)(nt * 32 + l31) * 16 + g;
            half8 bh = Bh[bi], blo = Bl[bi];
            acc[nt] = __builtin_amdgcn_mfma_f32_32x32x16_f16(ah, bh, acc[nt], 0, 0, 0);
            acc[nt] = __builtin_amdgcn_mfma_f32_32x32x16_f16(al, bh, acc[nt], 0, 0, 0);
            acc[nt] = __builtin_amdgcn_mfma_f32_32x32x16_f16(ah, blo, acc[nt], 0, 0, 0);
        }
    }

#pragma unroll
    for (int r = 0; r < 16; ++r) {
        int rl = (r & 3) + 8 * (r >> 2) + 4 * lhi;
        int row = n0 + rl;
        int g = __shfl(gl, rl, 32);  // stripe-row rl's graph id
        float ss = 0.f, sd = 0.f;
#pragma unroll
        for (int nt = 0; nt < 4; ++nt) {
            float y = acc[nt][r];
            float q = qs[g * H + nt * 32 + l31];
            ss = fmaf(y, y, ss);
            sd = fmaf(y, q, sd);
        }
#pragma unroll
        for (int off = 1; off <= 16; off <<= 1) {  // stays within 32-lane group
            ss += __shfl_xor(ss, off, 64);
            sd += __shfl_xor(sd, off, 64);
        }
        if (l31 == 0 && row < N) out[row] = sd / fmaxf(sqrtf(ss), 1e-12f);
    }
}

// ---------------- launch ----------------

extern "C" void kernel_launch(void* const* d_in, const int* in_sizes, int n_in,
                              void* d_out, int out_size, void* d_ws, size_t ws_size,
                              hipStream_t stream) {
    const float* x = (const float*)d_in[0];
    const float* query = (const float*)d_in[1];
    const float* Wl = (const float*)d_in[2];
    const float* bl = (const float*)d_in[3];
    const float* Wr = (const float*)d_in[4];
    const float* Wlin = (const float*)d_in[5];
    const float* blin = (const float*)d_in[6];
    const int* ei = (const int*)d_in[7];
    const int* bv = (const int*)d_in[8];
    float* out = (float*)d_out;

    const int N = in_sizes[0] / H;
    const int E = in_sizes[7] / 2;
    const int G = in_sizes[1] / H;
    const int NB = (N + 255) / 256;

    char* p = (char*)d_ws;
    auto alloc = [&](size_t bytes) {
        char* r = p;
        p += (bytes + 255) & ~(size_t)255;
        return r;
    };
    int* deg = (int*)alloc((size_t)2 * N * sizeof(int));  // deg then cursor
    int* cursor = deg + N;
    int* offsets = (int*)alloc((size_t)(N + 1) * sizeof(int));
    int* bsum = (int*)alloc((size_t)NB * sizeof(int));
    int* bbase = (int*)alloc((size_t)NB * sizeof(int));
    int* adj = (int*)alloc((size_t)E * sizeof(int));
    float* qn = (float*)alloc((size_t)G * H * sizeof(float));
    _Float16* wimg = (_Float16*)alloc((size_t)7 * 32768 * sizeof(_Float16));
    size_t actH = (size_t)N * H * sizeof(_Float16);
    _Float16* xah = (_Float16*)alloc(actH);
    _Float16* xal = (_Float16*)alloc(actH);
    _Float16* xbh = (_Float16*)alloc(actH);
    _Float16* xbl = (_Float16*)alloc(actH);
    _Float16* mh = (_Float16*)alloc(actH);
    _Float16* ml = (_Float16*)alloc(actH);

    zero_ints<<<(2 * N + 255) / 256, 256, 0, stream>>>(deg, 2 * N);
    hist_deg<<<(E + 255) / 256, 256, 0, stream>>>(ei, E, deg);
    block_sums<<<NB, 256, 0, stream>>>(deg, bsum, N);
    scan_bsum<<<1, 64, 0, stream>>>(bsum, bbase, NB, offsets + N);
    scan_within<<<NB, 256, 0, stream>>>(deg, bbase, offsets, N);
    fill_adj<<<(E + 255) / 256, 256, 0, stream>>>(ei, E, offsets, cursor, adj);
    prep_query<<<G, 128, 0, stream>>>(query, qn);
    prep_wsplit<<<(7 * 2048 + 255) / 256, 256, 0, stream>>>(Wl, Wr, Wlin, wimg);

    const int n8 = N * H / 8;
    split_x<<<(n8 + 255) / 256, 256, 0, stream>>>((const float4*)x, (half8*)xah,
                                                  (half8*)xal, n8);

    auto WH = [&](int mat) { return (const half8*)(wimg + (size_t)mat * 32768); };
    auto WLo = [&](int mat) {
        return (const half8*)(wimg + (size_t)mat * 32768 + 16384);
    };

    const int NGg = (N + 15) / 16;
    const int NGm = (N + 31) / 32;
    const int NGf = (N + 127) / 128;

    // layer 1: A set -> B set
    gather_max_h<<<NGg, 256, 0, stream>>>((const half8*)xah, (const half8*)xal,
                                          offsets, adj, (half8*)mh, (half8*)ml, N);
    gemm_mfma2<<<NGm, 256, 0, stream>>>(
        (const half8*)mh, (const half8*)ml, (const half8*)xah, (const half8*)xal,
        WH(0), WLo(0), WH(1), WLo(1), bl + 0 * H, xbh, xbl, N);
    // layer 2: B set -> A set
    gather_max_h<<<NGg, 256, 0, stream>>>((const half8*)xbh, (const half8*)xbl,
                                          offsets, adj, (half8*)mh, (half8*)ml, N);
    gemm_mfma2<<<NGm, 256, 0, stream>>>(
        (const half8*)mh, (const half8*)ml, (const half8*)xbh, (const half8*)xbl,
        WH(2), WLo(2), WH(3), WLo(3), bl + 1 * H, xah, xal, N);
    // layer 3: A set -> B set
    gather_max_h<<<NGg, 256, 0, stream>>>((const half8*)xah, (const half8*)xal,
                                          offsets, adj, (half8*)mh, (half8*)ml, N);
    gemm_mfma2<<<NGm, 256, 0, stream>>>(
        (const half8*)mh, (const half8*)ml, (const half8*)xah, (const half8*)xal,
        WH(4), WLo(4), WH(5), WLo(5), bl + 2 * H, xbh, xbl, N);
    // final
    final_mfma2<<<NGf, 256, 0, stream>>>((const half8*)xbh, (const half8*)xbl,
                                         WH(6), WLo(6), blin, qn, bv, out, N, G);
}

// Round 7
// 389.196 us; speedup vs baseline: 1.2853x; 1.2853x over previous
//
#include <hip/hip_runtime.h>
#include <math.h>

#define H 128

typedef _Float16 half8 __attribute__((ext_vector_type(8)));
typedef _Float16 half4 __attribute__((ext_vector_type(4)));
typedef float f32x16 __attribute__((ext_vector_type(16)));

// ---------------- CSR build ----------------

__global__ __launch_bounds__(256) void zero_ints(int* __restrict__ p, int n) {
    int i = blockIdx.x * 256 + threadIdx.x;
    if (i < n) p[i] = 0;
}

__global__ __launch_bounds__(256) void hist_deg(const int* __restrict__ ei, int E,
                                                int* __restrict__ deg) {
    int e = blockIdx.x * 256 + threadIdx.x;
    if (e < E) atomicAdd(&deg[ei[E + e]], 1);  // dst row of edge_index
}

__global__ __launch_bounds__(256) void block_sums(const int* __restrict__ deg,
                                                  int* __restrict__ bsum, int N) {
    __shared__ int part[4];
    int tid = threadIdx.x;
    int i = blockIdx.x * 256 + tid;
    int v = (i < N) ? deg[i] : 0;
#pragma unroll
    for (int off = 32; off > 0; off >>= 1) v += __shfl_down(v, off, 64);
    if ((tid & 63) == 0) part[tid >> 6] = v;
    __syncthreads();
    if (tid == 0) bsum[blockIdx.x] = part[0] + part[1] + part[2] + part[3];
}

__global__ __launch_bounds__(64) void scan_bsum(const int* __restrict__ bsum,
                                                int* __restrict__ bbase, int NB,
                                                int* __restrict__ totalOut) {
    int lane = threadIdx.x;
    int base = 0;
    for (int s0 = 0; s0 < NB; s0 += 64) {
        int i = s0 + lane;
        int v = (i < NB) ? bsum[i] : 0;
        int incl = v;
#pragma unroll
        for (int off = 1; off < 64; off <<= 1) {
            int t = __shfl_up(incl, off, 64);
            if (lane >= off) incl += t;
        }
        if (i < NB) bbase[i] = base + incl - v;
        base += __shfl(incl, 63, 64);
    }
    if (lane == 0) *totalOut = base;  // offsets[N] = E
}

__global__ __launch_bounds__(256) void scan_within(const int* __restrict__ deg,
                                                   const int* __restrict__ bbase,
                                                   int* __restrict__ offsets, int N) {
    __shared__ int buf[256];
    int tid = threadIdx.x;
    int i = blockIdx.x * 256 + tid;
    int v = (i < N) ? deg[i] : 0;
    int incl = v;
    buf[tid] = v;
    __syncthreads();
#pragma unroll
    for (int off = 1; off < 256; off <<= 1) {
        int t = (tid >= off) ? buf[tid - off] : 0;
        __syncthreads();
        incl += t;
        buf[tid] = incl;
        __syncthreads();
    }
    if (i < N) offsets[i] = bbase[blockIdx.x] + incl - v;  // exclusive scan
}

__global__ __launch_bounds__(256) void fill_adj(const int* __restrict__ ei, int E,
                                                const int* __restrict__ offsets,
                                                int* __restrict__ cursor,
                                                int* __restrict__ adj) {
    int e = blockIdx.x * 256 + threadIdx.x;
    if (e < E) {
        int s = ei[e];
        int d = ei[E + e];
        int pos = atomicAdd(&cursor[d], 1);
        adj[offsets[d] + pos] = s;
    }
}

// ---------------- query normalization ----------------

__global__ __launch_bounds__(128) void prep_query(const float* __restrict__ query,
                                                  float* __restrict__ qn) {
    int g = blockIdx.x;
    int f = threadIdx.x;
    float v = query[g * H + f];
    float ss = v * v;
#pragma unroll
    for (int off = 32; off > 0; off >>= 1) ss += __shfl_xor(ss, off, 64);
    __shared__ float part[2];
    if ((f & 63) == 0) part[f >> 6] = ss;
    __syncthreads();
    float tot = part[0] + part[1];
    qn[g * H + f] = v / fmaxf(sqrtf(tot), 1e-12f);
}

// ---------------- weight split into swizzled, K-chunked LDS images ----------
// mat order: Wl0,Wr0,Wl1,Wr1,Wl2,Wr2,Wlin. Address of (mat, kc, hl):
//   ((mat*2 + kc)*2 + hl) * 8192 halves   (= mat*32768 + kc*16384 + hl*8192)
// Chunk image layout: [n][pos*8] halves, pos = gp ^ (n&7), gp = granule
// within chunk (8 halves of k). One chunk image = 128 x 64 halves = 16 KB.

__global__ __launch_bounds__(256) void prep_wsplit(const float* __restrict__ Wl,
                                                   const float* __restrict__ Wr,
                                                   const float* __restrict__ Wlin,
                                                   _Float16* __restrict__ img) {
    int gidx = blockIdx.x * 256 + threadIdx.x;
    if (gidx >= 7 * 128 * 16) return;
    int mat = gidx / 2048;
    int rem = gidx - mat * 2048;
    int n = rem >> 4;
    int g = rem & 15;  // global granule [0,16)
    const float* src = (mat == 6) ? Wlin
                     : ((mat & 1) ? Wr + (mat >> 1) * H * H : Wl + (mat >> 1) * H * H);
    const float* p = src + n * H + g * 8;
    half8 h, l;
#pragma unroll
    for (int j = 0; j < 8; ++j) {
        float v = p[j];
        _Float16 hh = (_Float16)v;
        h[j] = hh;
        l[j] = (_Float16)(v - (float)hh);
    }
    int kc = g >> 3, gp = g & 7;
    int pos = gp ^ (n & 7);
    size_t cbase = (((size_t)mat * 2 + kc) * 2) * 8192 + (size_t)n * 64 + pos * 8;
    *(half8*)(img + cbase) = h;           // hi
    *(half8*)(img + cbase + 8192) = l;    // lo
}

// ---------------- gather-max (segment max over CSR, fp32) ----------------
// 32 lanes per node (float4 each), 8 nodes per 256-thread block.
// Clamp trick: out-of-range lanes re-read e1-1 (dupes are max-neutral).

__device__ __forceinline__ float4 f4max(float4 a, float4 b) {
    float4 r;
    r.x = fmaxf(a.x, b.x);
    r.y = fmaxf(a.y, b.y);
    r.z = fmaxf(a.z, b.z);
    r.w = fmaxf(a.w, b.w);
    return r;
}

__global__ __launch_bounds__(256) void gather_max(
    const float4* __restrict__ xin4, const int* __restrict__ offsets,
    const int* __restrict__ adj, float4* __restrict__ m4, int N) {
    int tid = threadIdx.x;
    int f4 = tid & 31;
    int node = blockIdx.x * 8 + (tid >> 5);
    if (node >= N) return;
    int e0 = offsets[node], e1 = offsets[node + 1];
    float4 b = make_float4(0.f, 0.f, 0.f, 0.f);
    if (e1 > e0) {
        const float4 ninf = make_float4(-INFINITY, -INFINITY, -INFINITY, -INFINITY);
        float4 acc[8];
#pragma unroll
        for (int u = 0; u < 8; ++u) acc[u] = ninf;
        for (int base = e0; base < e1; base += 8) {
            int a[8];
#pragma unroll
            for (int u = 0; u < 8; ++u) {
                int ee = base + u;
                a[u] = adj[ee < e1 ? ee : e1 - 1];
            }
            float4 v[8];
#pragma unroll
            for (int u = 0; u < 8; ++u) v[u] = xin4[(size_t)a[u] * 32 + f4];
#pragma unroll
            for (int u = 0; u < 8; ++u) acc[u] = f4max(acc[u], v[u]);
        }
#pragma unroll
        for (int u = 4; u < 8; ++u) acc[u - 4] = f4max(acc[u - 4], acc[u]);
        b = f4max(f4max(acc[0], acc[1]), f4max(acc[2], acc[3]));
    }
    m4[(size_t)node * 32 + f4] = b;
}

// ---------------- MFMA dual GEMM + bias + relu, LDS-staged, K-chunked ------
// relu(A0 @ Wl^T + bias + A1 @ Wr^T), split-fp16 x3 MFMA, fp32 in/out.
// Block 256 = 4 waves; tile 64 rows x 128 cols; 2 passes x 2 k-chunks (64 k).
// Wave w: row stripe (w>>1), col half (w&1) -> 2 32x32 acc tiles.
// LDS: sA 16 KB + sB 32 KB = 48 KB -> 3 blocks/CU.

__global__ __launch_bounds__(256) void gemm_mfma4(
    const float* __restrict__ A0, const float* __restrict__ A1,
    const _Float16* __restrict__ Bimg,  // layer base (2 mats, chunked)
    const float* __restrict__ bias, float* __restrict__ xout, int N) {
    __shared__ __align__(16) _Float16 sA[2][4096];  // [hl][row*64 + pos*8], 64 rows
    __shared__ __align__(16) _Float16 sB[2][8192];  // [hl][n*64 + pos*8], 128 cols

    int tid = threadIdx.x;
    int w = tid >> 6;
    int lane = tid & 63;
    int l31 = lane & 31;
    int lhi = lane >> 5;
    int ws = w >> 1;  // row stripe (32 rows)
    int wc = w & 1;   // col half (64 cols)
    int n0 = blockIdx.x * 64;

    f32x16 acc[2];
#pragma unroll
    for (int nt = 0; nt < 2; ++nt) {
        float bv = bias[wc * 64 + nt * 32 + l31];
#pragma unroll
        for (int r = 0; r < 16; ++r) acc[nt][r] = bv;
    }

    int rl = ws * 32 + l31;  // this lane's A row within the tile

    for (int pass = 0; pass < 2; ++pass) {
        const float4* A4 = (const float4*)(pass ? A1 : A0);
        for (int kc = 0; kc < 2; ++kc) {
            __syncthreads();  // previous chunk done reading LDS
            // stage B chunk: straight 32 KB copy (hi 16 KB + lo 16 KB)
            {
                const half8* bsrc =
                    (const half8*)(Bimg + (size_t)pass * 32768 + kc * 16384);
                half8* bdst = (half8*)&sB[0][0];
#pragma unroll
                for (int i = 0; i < 8; ++i) bdst[tid + i * 256] = bsrc[tid + i * 256];
            }
            // stage A chunk: coalesced fp32 read, split, swizzled LDS write
#pragma unroll
            for (int i = 0; i < 4; ++i) {
                int idx = tid + i * 256;  // [0,1024)
                int row = idx >> 4;       // [0,64)
                int f4l = idx & 15;       // float4 within chunk
                int n = n0 + row;
                float4 v = make_float4(0.f, 0.f, 0.f, 0.f);
                if (n < N) v = A4[(size_t)n * 32 + kc * 16 + f4l];
                float f[4] = {v.x, v.y, v.z, v.w};
                half4 h, l;
#pragma unroll
                for (int j = 0; j < 4; ++j) {
                    _Float16 hh = (_Float16)f[j];
                    h[j] = hh;
                    l[j] = (_Float16)(f[j] - (float)hh);
                }
                int gp = f4l >> 1;
                int pos = gp ^ (row & 7);
                int off = row * 64 + pos * 8 + (f4l & 1) * 4;
                *(half4*)&sA[0][off] = h;
                *(half4*)&sA[1][off] = l;
            }
            __syncthreads();

#pragma unroll
            for (int ks = 0; ks < 4; ++ks) {
                int gp = ks * 2 + lhi;
                int posA = gp ^ (rl & 7);
                half8 ah = *(const half8*)&sA[0][rl * 64 + posA * 8];
                half8 al = *(const half8*)&sA[1][rl * 64 + posA * 8];
#pragma unroll
                for (int nt = 0; nt < 2; ++nt) {
                    int n = wc * 64 + nt * 32 + l31;
                    int posB = gp ^ (n & 7);
                    half8 bh = *(const half8*)&sB[0][n * 64 + posB * 8];
                    half8 bl = *(const half8*)&sB[1][n * 64 + posB * 8];
                    acc[nt] = __builtin_amdgcn_mfma_f32_32x32x16_f16(ah, bh, acc[nt], 0, 0, 0);
                    acc[nt] = __builtin_amdgcn_mfma_f32_32x32x16_f16(al, bh, acc[nt], 0, 0, 0);
                    acc[nt] = __builtin_amdgcn_mfma_f32_32x32x16_f16(ah, bl, acc[nt], 0, 0, 0);
                }
            }
        }
    }

    // C/D: col = l31 (+base), row = (r&3) + 8*(r>>2) + 4*lhi (+stripe)
#pragma unroll
    for (int r = 0; r < 16; ++r) {
        int row = n0 + ws * 32 + (r & 3) + 8 * (r >> 2) + 4 * lhi;
        if (row < N) {
#pragma unroll
            for (int nt = 0; nt < 2; ++nt) {
                int col = wc * 64 + nt * 32 + l31;
                xout[(size_t)row * H + col] = fmaxf(acc[nt][r], 0.f);
            }
        }
    }
}

// ---------------- MFMA final linear + cosine, LDS-staged, K-chunked --------
// Block 256 = 4 waves; each wave an independent 32-row stripe x 128 cols
// (nt=4) so the cosine reduction stays within 32 lanes. 128 rows/block.
// LDS: sA 32 KB + sB 32 KB = 64 KB exactly. qn read from global (L2, 4 KB).

__global__ __launch_bounds__(256) void final_mfma4(
    const float* __restrict__ xin, const _Float16* __restrict__ Bimg,  // Wlin
    const float* __restrict__ blin, const float* __restrict__ qn,
    const int* __restrict__ bv, float* __restrict__ out, int N) {
    __shared__ __align__(16) _Float16 sA[2][8192];  // [hl][row*64 + pos*8], 128 rows
    __shared__ __align__(16) _Float16 sB[2][8192];  // [hl][n*64 + pos*8], 128 cols

    int tid = threadIdx.x;
    int w = tid >> 6;
    int lane = tid & 63;
    int l31 = lane & 31;
    int lhi = lane >> 5;
    int n0 = blockIdx.x * 128;

    int arow = n0 + w * 32 + l31;
    arow = arow < N ? arow : N - 1;
    int gl = bv[arow];  // stripe's graph ids, indexed by l31

    f32x16 acc[4];
#pragma unroll
    for (int nt = 0; nt < 4; ++nt) {
        float b = blin[nt * 32 + l31];
#pragma unroll
        for (int r = 0; r < 16; ++r) acc[nt][r] = b;
    }

    int rl = w * 32 + l31;
    const float4* A4 = (const float4*)xin;

    for (int kc = 0; kc < 2; ++kc) {
        __syncthreads();
        // stage B chunk
        {
            const half8* bsrc = (const half8*)(Bimg + (size_t)kc * 16384);
            half8* bdst = (half8*)&sB[0][0];
#pragma unroll
            for (int i = 0; i < 8; ++i) bdst[tid + i * 256] = bsrc[tid + i * 256];
        }
        // stage A chunk: 128 rows x 16 float4
#pragma unroll
        for (int i = 0; i < 8; ++i) {
            int idx = tid + i * 256;  // [0,2048)
            int row = idx >> 4;       // [0,128)
            int f4l = idx & 15;
            int n = n0 + row;
            float4 v = make_float4(0.f, 0.f, 0.f, 0.f);
            if (n < N) v = A4[(size_t)n * 32 + kc * 16 + f4l];
            float f[4] = {v.x, v.y, v.z, v.w};
            half4 h, l;
#pragma unroll
            for (int j = 0; j < 4; ++j) {
                _Float16 hh = (_Float16)f[j];
                h[j] = hh;
                l[j] = (_Float16)(f[j] - (float)hh);
            }
            int gp = f4l >> 1;
            int pos = gp ^ (row & 7);
            int off = row * 64 + pos * 8 + (f4l & 1) * 4;
            *(half4*)&sA[0][off] = h;
            *(half4*)&sA[1][off] = l;
        }
        __syncthreads();

#pragma unroll
        for (int ks = 0; ks < 4; ++ks) {
            int gp = ks * 2 + lhi;
            int posA = gp ^ (rl & 7);
            half8 ah = *(const half8*)&sA[0][rl * 64 + posA * 8];
            half8 al = *(const half8*)&sA[1][rl * 64 + posA * 8];
#pragma unroll
            for (int nt = 0; nt < 4; ++nt) {
                int n = nt * 32 + l31;
                int posB = gp ^ (n & 7);
                half8 bh = *(const half8*)&sB[0][n * 64 + posB * 8];
                half8 bl = *(const half8*)&sB[1][n * 64 + posB * 8];
                acc[nt] = __builtin_amdgcn_mfma_f32_32x32x16_f16(ah, bh, acc[nt], 0, 0, 0);
                acc[nt] = __builtin_amdgcn_mfma_f32_32x32x16_f16(al, bh, acc[nt], 0, 0, 0);
                acc[nt] = __builtin_amdgcn_mfma_f32_32x32x16_f16(ah, bl, acc[nt], 0, 0, 0);
            }
        }
    }

    // cosine epilogue: row rloc owned by 32 lanes (l31); xor<=16 stays in group
#pragma unroll
    for (int r = 0; r < 16; ++r) {
        int rloc = (r & 3) + 8 * (r >> 2) + 4 * lhi;
        int row = n0 + w * 32 + rloc;
        int g = __shfl(gl, rloc, 32);  // stripe-row rloc's graph id
        float ss = 0.f, sd = 0.f;
#pragma unroll
        for (int nt = 0; nt < 4; ++nt) {
            float y = acc[nt][r];
            float q = qn[(size_t)g * H + nt * 32 + l31];
            ss = fmaf(y, y, ss);
            sd = fmaf(y, q, sd);
        }
#pragma unroll
        for (int off = 1; off <= 16; off <<= 1) {
            ss += __shfl_xor(ss, off, 64);
            sd += __shfl_xor(sd, off, 64);
        }
        if (l31 == 0 && row < N) out[row] = sd / fmaxf(sqrtf(ss), 1e-12f);
    }
}

// ---------------- launch ----------------

extern "C" void kernel_launch(void* const* d_in, const int* in_sizes, int n_in,
                              void* d_out, int out_size, void* d_ws, size_t ws_size,
                              hipStream_t stream) {
    const float* x = (const float*)d_in[0];
    const float* query = (const float*)d_in[1];
    const float* Wl = (const float*)d_in[2];
    const float* bl = (const float*)d_in[3];
    const float* Wr = (const float*)d_in[4];
    const float* Wlin = (const float*)d_in[5];
    const float* blin = (const float*)d_in[6];
    const int* ei = (const int*)d_in[7];
    const int* bv = (const int*)d_in[8];
    float* out = (float*)d_out;

    const int N = in_sizes[0] / H;
    const int E = in_sizes[7] / 2;
    const int G = in_sizes[1] / H;
    const int NB = (N + 255) / 256;

    char* p = (char*)d_ws;
    auto alloc = [&](size_t bytes) {
        char* r = p;
        p += (bytes + 255) & ~(size_t)255;
        return r;
    };
    int* deg = (int*)alloc((size_t)2 * N * sizeof(int));  // deg then cursor
    int* cursor = deg + N;
    int* offsets = (int*)alloc((size_t)(N + 1) * sizeof(int));
    int* bsum = (int*)alloc((size_t)NB * sizeof(int));
    int* bbase = (int*)alloc((size_t)NB * sizeof(int));
    int* adj = (int*)alloc((size_t)E * sizeof(int));
    float* qn = (float*)alloc((size_t)G * H * sizeof(float));
    _Float16* wimg = (_Float16*)alloc((size_t)7 * 32768 * sizeof(_Float16));
    float* mbuf = (float*)alloc((size_t)N * H * sizeof(float));
    float* xb0 = (float*)alloc((size_t)N * H * sizeof(float));
    float* xb1 = (float*)alloc((size_t)N * H * sizeof(float));

    zero_ints<<<(2 * N + 255) / 256, 256, 0, stream>>>(deg, 2 * N);
    hist_deg<<<(E + 255) / 256, 256, 0, stream>>>(ei, E, deg);
    block_sums<<<NB, 256, 0, stream>>>(deg, bsum, N);
    scan_bsum<<<1, 64, 0, stream>>>(bsum, bbase, NB, offsets + N);
    scan_within<<<NB, 256, 0, stream>>>(deg, bbase, offsets, N);
    fill_adj<<<(E + 255) / 256, 256, 0, stream>>>(ei, E, offsets, cursor, adj);
    prep_query<<<G, 128, 0, stream>>>(query, qn);
    prep_wsplit<<<(7 * 2048 + 255) / 256, 256, 0, stream>>>(Wl, Wr, Wlin, wimg);

    const int NGg = (N + 7) / 8;      // gather blocks
    const int NGm = (N + 63) / 64;    // gemm blocks
    const int NGf = (N + 127) / 128;  // final blocks

    // per-layer weight base: 2 mats x 32768 halves
    gather_max<<<NGg, 256, 0, stream>>>((const float4*)x, offsets, adj,
                                        (float4*)mbuf, N);
    gemm_mfma4<<<NGm, 256, 0, stream>>>(mbuf, x, wimg + (size_t)0 * 65536,
                                        bl + 0 * H, xb0, N);
    gather_max<<<NGg, 256, 0, stream>>>((const float4*)xb0, offsets, adj,
                                        (float4*)mbuf, N);
    gemm_mfma4<<<NGm, 256, 0, stream>>>(mbuf, xb0, wimg + (size_t)1 * 65536,
                                        bl + 1 * H, xb1, N);
    gather_max<<<NGg, 256, 0, stream>>>((const float4*)xb1, offsets, adj,
                                        (float4*)mbuf, N);
    gemm_mfma4<<<NGm, 256, 0, stream>>>(mbuf, xb1, wimg + (size_t)2 * 65536,
                                        bl + 2 * H, xb0, N);
    final_mfma4<<<NGf, 256, 0, stream>>>(xb0, wimg + (size_t)6 * 32768, blin, qn,
                                         bv, out, N);
}